// Round 1
// baseline (1515.890 us; speedup 1.0000x reference)
//
#include <hip/hip_runtime.h>

#define DIM 1024
#define BATCH 4096

// Register layout for a 1024-elem row held by one wave (64 lanes):
//   reg r = q*4 + j  <->  element q*256 + lane*4 + j   (q in 0..3, j in 0..3)
// Chunk q covers elements [q*256, q*256+255] -> uniform suffix skip at i>>8.

__device__ __forceinline__ void prefetch_row(float (&u)[16], const float* __restrict__ src,
                                             int lane, int cmin) {
#pragma unroll
  for (int q = 0; q < 4; ++q) {
    if (q >= cmin) {
      float4 v = *reinterpret_cast<const float4*>(src + q * 256 + lane * 4);
      u[q * 4 + 0] = v.x; u[q * 4 + 1] = v.y; u[q * 4 + 2] = v.z; u[q * 4 + 3] = v.w;
    }
  }
}

__device__ __forceinline__ void reflect(float (&t)[16], const float (&u)[16],
                                        float tin, int cmin) {
  float d0 = 0.f, d1 = 0.f, d2 = 0.f, d3 = 0.f;
#pragma unroll
  for (int q = 0; q < 4; ++q) {
    if (q >= cmin) {
      d0 += t[q * 4 + 0] * u[q * 4 + 0];
      d1 += t[q * 4 + 1] * u[q * 4 + 1];
      d2 += t[q * 4 + 2] * u[q * 4 + 2];
      d3 += t[q * 4 + 3] * u[q * 4 + 3];
    }
  }
  float dot = (d0 + d1) + (d2 + d3);
#pragma unroll
  for (int off = 32; off; off >>= 1) dot += __shfl_xor(dot, off);
  float alpha = dot * tin;  // tin = 2/||u||^2
#pragma unroll
  for (int q = 0; q < 4; ++q) {
    if (q >= cmin) {
      t[q * 4 + 0] -= alpha * u[q * 4 + 0];
      t[q * 4 + 1] -= alpha * u[q * 4 + 1];
      t[q * 4 + 2] -= alpha * u[q * 4 + 2];
      t[q * 4 + 3] -= alpha * u[q * 4 + 3];
    }
  }
}

// 2/||row||^2 for all rows of U and V. One wave per row.
__global__ __launch_bounds__(256) void prep_k(const float* __restrict__ U,
                                              const float* __restrict__ V,
                                              float* __restrict__ tinu,
                                              float* __restrict__ tinv) {
  int gw = (blockIdx.x * 256 + threadIdx.x) >> 6;
  int lane = threadIdx.x & 63;
  if (gw >= 2048) return;
  const float* src = (gw < 1024) ? (U + (size_t)gw * DIM) : (V + (size_t)(gw - 1024) * DIM);
  float s = 0.f;
#pragma unroll
  for (int q = 0; q < 4; ++q) {
    float4 v = *reinterpret_cast<const float4*>(src + q * 256 + lane * 4);
    s += v.x * v.x + v.y * v.y + v.z * v.z + v.w * v.w;
  }
#pragma unroll
  for (int off = 32; off; off >>= 1) s += __shfl_xor(s, off);
  if (lane == 0) {
    float val = 2.0f / s;
    if (gw < 1024) tinu[gw] = val; else tinv[gw - 1024] = val;
  }
}

__global__ __launch_bounds__(256) void sig_k(const float* __restrict__ p, float* __restrict__ sg) {
  int i = blockIdx.x * 256 + threadIdx.x;
  if (i < DIM) {
    // 2*r*(sigmoid(p)-0.5)+sigma_mean with r=0.45, mean=0.55  ->  0.9*sigmoid(p)+0.1
    sg[i] = 0.1f + 0.9f / (1.0f + __expf(-p[i]));
  }
}

// Build M = Q_U * diag(sig) * Q_V by running both Householder chains on identity rows.
// One wave per row; row lives in 16 VGPRs; reflector rows double-buffered in regs.
__global__ __launch_bounds__(64) void chain_k(const float* __restrict__ U,
                                              const float* __restrict__ V,
                                              const float* __restrict__ tinu,
                                              const float* __restrict__ tinv,
                                              const float* __restrict__ sg,
                                              float* __restrict__ M) {
  const int row = blockIdx.x;
  const int lane = threadIdx.x;
  float t[16];
#pragma unroll
  for (int q = 0; q < 4; ++q)
#pragma unroll
    for (int j = 0; j < 4; ++j)
      t[q * 4 + 3 - 3 + j] = ((q * 256 + lane * 4 + j) == row) ? 1.0f : 0.0f;

  float ua[16], ub[16];
  // ---- U chain: i = 0 .. 1023 ----
  prefetch_row(ua, U, lane, 0);
  for (int i = 0; i < DIM; i += 2) {
    float tin0 = tinu[i];
    float tin1 = tinu[i + 1];
    prefetch_row(ub, U + (size_t)(i + 1) * DIM, lane, (i + 1) >> 8);
    reflect(t, ua, tin0, i >> 8);
    if (i + 2 < DIM) prefetch_row(ua, U + (size_t)(i + 2) * DIM, lane, (i + 2) >> 8);
    reflect(t, ub, tin1, (i + 1) >> 8);
  }
  // ---- sigma scaling (columns) ----
#pragma unroll
  for (int q = 0; q < 4; ++q) {
    float4 v = *reinterpret_cast<const float4*>(sg + q * 256 + lane * 4);
    t[q * 4 + 0] *= v.x; t[q * 4 + 1] *= v.y; t[q * 4 + 2] *= v.z; t[q * 4 + 3] *= v.w;
  }
  // ---- V chain reversed: i = 1023 .. 0 ----
  prefetch_row(ua, V + (size_t)(DIM - 1) * DIM, lane, (DIM - 1) >> 8);
  for (int i = DIM - 1; i > 0; i -= 2) {
    float tin0 = tinv[i];
    float tin1 = tinv[i - 1];
    prefetch_row(ub, V + (size_t)(i - 1) * DIM, lane, (i - 1) >> 8);
    reflect(t, ua, tin0, i >> 8);
    if (i - 2 >= 0) prefetch_row(ua, V + (size_t)(i - 2) * DIM, lane, (i - 2) >> 8);
    reflect(t, ub, tin1, (i - 1) >> 8);
  }
  // ---- store row of M ----
#pragma unroll
  for (int q = 0; q < 4; ++q) {
    float4 v;
    v.x = t[q * 4 + 0]; v.y = t[q * 4 + 1]; v.z = t[q * 4 + 2]; v.w = t[q * 4 + 3];
    *reinterpret_cast<float4*>(M + (size_t)row * DIM + q * 256 + lane * 4) = v;
  }
}

// out[4096,1024] = x[4096,1024] @ M[1024,1024] + bias, f32 vector GEMM.
// 128x128 block tile, BK=16, 256 threads, 8x8 per-thread microtile.
__global__ __launch_bounds__(256) void gemm_k(const float* __restrict__ A,
                                              const float* __restrict__ Bm,
                                              const float* __restrict__ bias,
                                              float* __restrict__ C) {
  __shared__ float As[16][132];  // [k][m], padded
  __shared__ float Bs[16][132];  // [k][n], padded
  const int tid = threadIdx.x;
  const int tx = tid & 15;
  const int ty = tid >> 4;
  const int bn = blockIdx.x;  // 0..7
  const int bm = blockIdx.y;  // 0..31
  const float* Ab = A + (size_t)bm * 128 * DIM;
  const float* Bb = Bm + (size_t)bn * 128;
  float acc[8][8] = {};

  for (int kb = 0; kb < DIM; kb += 16) {
    __syncthreads();
#pragma unroll
    for (int ii = 0; ii < 2; ++ii) {
      int f = tid + ii * 256;
      // A tile: 128 rows x 16 k  (512 float4)
      int r = f >> 2, k4 = (f & 3) << 2;
      float4 va = *reinterpret_cast<const float4*>(Ab + (size_t)r * DIM + kb + k4);
      As[k4 + 0][r] = va.x; As[k4 + 1][r] = va.y; As[k4 + 2][r] = va.z; As[k4 + 3][r] = va.w;
      // B tile: 16 k x 128 n  (512 float4)
      int kB = f >> 5, n4 = (f & 31) << 2;
      float4 vb = *reinterpret_cast<const float4*>(Bb + (size_t)(kb + kB) * DIM + n4);
      *reinterpret_cast<float4*>(&Bs[kB][n4]) = vb;
    }
    __syncthreads();
#pragma unroll
    for (int kk = 0; kk < 16; ++kk) {
      float a[8], b[8];
#pragma unroll
      for (int m = 0; m < 8; ++m) a[m] = As[kk][ty * 8 + m];
#pragma unroll
      for (int n = 0; n < 8; ++n) b[n] = Bs[kk][tx * 8 + n];
#pragma unroll
      for (int m = 0; m < 8; ++m)
#pragma unroll
        for (int n = 0; n < 8; ++n) acc[m][n] += a[m] * b[n];
    }
  }

#pragma unroll
  for (int m = 0; m < 8; ++m) {
    int grow = bm * 128 + ty * 8 + m;
#pragma unroll
    for (int n4 = 0; n4 < 2; ++n4) {
      int gcol = bn * 128 + tx * 8 + n4 * 4;
      float4 o;
      o.x = acc[m][n4 * 4 + 0] + bias[gcol + 0];
      o.y = acc[m][n4 * 4 + 1] + bias[gcol + 1];
      o.z = acc[m][n4 * 4 + 2] + bias[gcol + 2];
      o.w = acc[m][n4 * 4 + 3] + bias[gcol + 3];
      *reinterpret_cast<float4*>(C + (size_t)grow * DIM + gcol) = o;
    }
  }
}

extern "C" void kernel_launch(void* const* d_in, const int* in_sizes, int n_in,
                              void* d_out, int out_size, void* d_ws, size_t ws_size,
                              hipStream_t stream) {
  const float* x    = (const float*)d_in[0];
  const float* U    = (const float*)d_in[1];
  const float* V    = (const float*)d_in[2];
  const float* p    = (const float*)d_in[3];
  const float* bias = (const float*)d_in[4];
  float* out = (float*)d_out;

  float* M    = (float*)d_ws;          // 1024*1024 f32 = 4 MB
  float* tinu = M + (size_t)DIM * DIM; // 1024
  float* tinv = tinu + DIM;            // 1024
  float* sg   = tinv + DIM;            // 1024

  prep_k<<<512, 256, 0, stream>>>(U, V, tinu, tinv);
  sig_k<<<DIM / 256, 256, 0, stream>>>(p, sg);
  chain_k<<<DIM, 64, 0, stream>>>(U, V, tinu, tinv, sg, M);
  gemm_k<<<dim3(8, 32), 256, 0, stream>>>(x, M, bias, out);
}

// Round 2
// 650.435 us; speedup vs baseline: 2.3306x; 2.3306x over previous
//
#include <hip/hip_runtime.h>

#define DIM 1024
#define BATCH 4096

// ---------------------------------------------------------------------------
// Wave-wide sum via DPP (VALU pipe, ~6cy/step) instead of __shfl_xor
// (ds_bpermute, ~120cy/step). Returns total as a wave-uniform value.
// Sequence: row_shr 1,2,4,8 then row_bcast:15, row_bcast:31 -> total in lane 63.
__device__ __forceinline__ float dpp_reduce_bcast(float x) {
  int v = __builtin_bit_cast(int, x);
#define DPP_STEP(ctrl)                                                        \
  {                                                                           \
    int s = __builtin_amdgcn_update_dpp(0, v, ctrl, 0xf, 0xf, true);          \
    v = __builtin_bit_cast(                                                   \
        int, __builtin_bit_cast(float, v) + __builtin_bit_cast(float, s));    \
  }
  DPP_STEP(0x111)  // row_shr:1
  DPP_STEP(0x112)  // row_shr:2
  DPP_STEP(0x114)  // row_shr:4
  DPP_STEP(0x118)  // row_shr:8
  DPP_STEP(0x142)  // row_bcast:15
  DPP_STEP(0x143)  // row_bcast:31
#undef DPP_STEP
  return __builtin_bit_cast(float, __builtin_amdgcn_readlane(v, 63));
}

// Register layout for a 1024-elem row held by one wave (64 lanes):
//   reg r = q*4 + j  <->  element q*256 + lane*4 + j   (q in 0..3, j in 0..3)
// No triangular skip: U/V inputs are already upper-triangular (exact zeros
// below the diagonal), so full-width dot/axpy is mathematically identical
// and branch-free (we are latency-bound, not FLOP-bound).

__device__ __forceinline__ void prefetch_row(float (&u)[16],
                                             const float* __restrict__ src,
                                             int lane) {
#pragma unroll
  for (int q = 0; q < 4; ++q) {
    float4 v = *reinterpret_cast<const float4*>(src + q * 256 + lane * 4);
    u[q * 4 + 0] = v.x; u[q * 4 + 1] = v.y; u[q * 4 + 2] = v.z; u[q * 4 + 3] = v.w;
  }
}

__device__ __forceinline__ void reflect(float (&t)[16], const float (&u)[16],
                                        float tin) {
  float d0 = 0.f, d1 = 0.f, d2 = 0.f, d3 = 0.f;
#pragma unroll
  for (int q = 0; q < 4; ++q) {
    d0 = fmaf(t[q * 4 + 0], u[q * 4 + 0], d0);
    d1 = fmaf(t[q * 4 + 1], u[q * 4 + 1], d1);
    d2 = fmaf(t[q * 4 + 2], u[q * 4 + 2], d2);
    d3 = fmaf(t[q * 4 + 3], u[q * 4 + 3], d3);
  }
  float a = dpp_reduce_bcast((d0 + d1) + (d2 + d3)) * tin;  // tin = 2/||u||^2
#pragma unroll
  for (int r = 0; r < 16; ++r) t[r] = fmaf(-a, u[r], t[r]);
}

// 2/||row||^2 for all rows of U and V. One wave per row.
__global__ __launch_bounds__(256) void prep_k(const float* __restrict__ U,
                                              const float* __restrict__ V,
                                              float* __restrict__ tinu,
                                              float* __restrict__ tinv) {
  int gw = (blockIdx.x * 256 + threadIdx.x) >> 6;
  int lane = threadIdx.x & 63;
  if (gw >= 2048) return;
  const float* src = (gw < 1024) ? (U + (size_t)gw * DIM) : (V + (size_t)(gw - 1024) * DIM);
  float s = 0.f;
#pragma unroll
  for (int q = 0; q < 4; ++q) {
    float4 v = *reinterpret_cast<const float4*>(src + q * 256 + lane * 4);
    s += v.x * v.x + v.y * v.y + v.z * v.z + v.w * v.w;
  }
  float tot = dpp_reduce_bcast(s);
  if (lane == 0) {
    float val = 2.0f / tot;
    if (gw < 1024) tinu[gw] = val; else tinv[gw - 1024] = val;
  }
}

__global__ __launch_bounds__(256) void sig_k(const float* __restrict__ p, float* __restrict__ sg) {
  int i = blockIdx.x * 256 + threadIdx.x;
  if (i < DIM) {
    // 2*r*(sigmoid(p)-0.5)+sigma_mean with r=0.45, mean=0.55 -> 0.9*sigmoid(p)+0.1
    sg[i] = 0.1f + 0.9f / (1.0f + __expf(-p[i]));
  }
}

// Build M = Q_U * diag(sig) * Q_V by running both Householder chains on
// identity rows. One wave per row; row in 16 VGPRs; reflector rows in a
// 4-deep register ring (prefetch distance ~3 reflections covers L2 latency).
__global__ __launch_bounds__(64, 1) void chain_k(const float* __restrict__ U,
                                                 const float* __restrict__ V,
                                                 const float* __restrict__ tinu,
                                                 const float* __restrict__ tinv,
                                                 const float* __restrict__ sg,
                                                 float* __restrict__ M) {
  const int row = blockIdx.x;
  const int lane = threadIdx.x;
  float t[16];
#pragma unroll
  for (int q = 0; q < 4; ++q)
#pragma unroll
    for (int j = 0; j < 4; ++j)
      t[q * 4 + j] = ((q * 256 + lane * 4 + j) == row) ? 1.0f : 0.0f;

  float u0[16], u1[16], u2[16], u3[16];

  // ---- U chain: i = 0 .. 1023 ----
  prefetch_row(u0, U + (size_t)0 * DIM, lane);
  prefetch_row(u1, U + (size_t)1 * DIM, lane);
  prefetch_row(u2, U + (size_t)2 * DIM, lane);
  prefetch_row(u3, U + (size_t)3 * DIM, lane);
  for (int i = 0; i < DIM; i += 4) {
    reflect(t, u0, tinu[i + 0]);
    if (i + 4 < DIM) prefetch_row(u0, U + (size_t)(i + 4) * DIM, lane);
    reflect(t, u1, tinu[i + 1]);
    if (i + 5 < DIM) prefetch_row(u1, U + (size_t)(i + 5) * DIM, lane);
    reflect(t, u2, tinu[i + 2]);
    if (i + 6 < DIM) prefetch_row(u2, U + (size_t)(i + 6) * DIM, lane);
    reflect(t, u3, tinu[i + 3]);
    if (i + 7 < DIM) prefetch_row(u3, U + (size_t)(i + 7) * DIM, lane);
  }

  // ---- sigma scaling (columns) ----
#pragma unroll
  for (int q = 0; q < 4; ++q) {
    float4 v = *reinterpret_cast<const float4*>(sg + q * 256 + lane * 4);
    t[q * 4 + 0] *= v.x; t[q * 4 + 1] *= v.y; t[q * 4 + 2] *= v.z; t[q * 4 + 3] *= v.w;
  }

  // ---- V chain reversed: i = 1023 .. 0 ----
  prefetch_row(u0, V + (size_t)(DIM - 1) * DIM, lane);
  prefetch_row(u1, V + (size_t)(DIM - 2) * DIM, lane);
  prefetch_row(u2, V + (size_t)(DIM - 3) * DIM, lane);
  prefetch_row(u3, V + (size_t)(DIM - 4) * DIM, lane);
  for (int i = DIM - 1; i > 0; i -= 4) {
    reflect(t, u0, tinv[i - 0]);
    if (i - 4 >= 0) prefetch_row(u0, V + (size_t)(i - 4) * DIM, lane);
    reflect(t, u1, tinv[i - 1]);
    if (i - 5 >= 0) prefetch_row(u1, V + (size_t)(i - 5) * DIM, lane);
    reflect(t, u2, tinv[i - 2]);
    if (i - 6 >= 0) prefetch_row(u2, V + (size_t)(i - 6) * DIM, lane);
    reflect(t, u3, tinv[i - 3]);
    if (i - 7 >= 0) prefetch_row(u3, V + (size_t)(i - 7) * DIM, lane);
  }

  // ---- store row of M ----
#pragma unroll
  for (int q = 0; q < 4; ++q) {
    float4 v;
    v.x = t[q * 4 + 0]; v.y = t[q * 4 + 1]; v.z = t[q * 4 + 2]; v.w = t[q * 4 + 3];
    *reinterpret_cast<float4*>(M + (size_t)row * DIM + q * 256 + lane * 4) = v;
  }
}

// out[4096,1024] = x[4096,1024] @ M[1024,1024] + bias, f32 vector GEMM.
// 128x128 block tile, BK=16, 256 threads, 8x8 per-thread microtile.
__global__ __launch_bounds__(256) void gemm_k(const float* __restrict__ A,
                                              const float* __restrict__ Bm,
                                              const float* __restrict__ bias,
                                              float* __restrict__ C) {
  __shared__ float As[16][132];  // [k][m], padded
  __shared__ float Bs[16][132];  // [k][n], padded
  const int tid = threadIdx.x;
  const int tx = tid & 15;
  const int ty = tid >> 4;
  const int bn = blockIdx.x;  // 0..7
  const int bm = blockIdx.y;  // 0..31
  const float* Ab = A + (size_t)bm * 128 * DIM;
  const float* Bb = Bm + (size_t)bn * 128;
  float acc[8][8] = {};

  for (int kb = 0; kb < DIM; kb += 16) {
    __syncthreads();
#pragma unroll
    for (int ii = 0; ii < 2; ++ii) {
      int f = tid + ii * 256;
      // A tile: 128 rows x 16 k  (512 float4)
      int r = f >> 2, k4 = (f & 3) << 2;
      float4 va = *reinterpret_cast<const float4*>(Ab + (size_t)r * DIM + kb + k4);
      As[k4 + 0][r] = va.x; As[k4 + 1][r] = va.y; As[k4 + 2][r] = va.z; As[k4 + 3][r] = va.w;
      // B tile: 16 k x 128 n  (512 float4)
      int kB = f >> 5, n4 = (f & 31) << 2;
      float4 vb = *reinterpret_cast<const float4*>(Bb + (size_t)(kb + kB) * DIM + n4);
      *reinterpret_cast<float4*>(&Bs[kB][n4]) = vb;
    }
    __syncthreads();
#pragma unroll
    for (int kk = 0; kk < 16; ++kk) {
      float a[8], b[8];
#pragma unroll
      for (int m = 0; m < 8; ++m) a[m] = As[kk][ty * 8 + m];
#pragma unroll
      for (int n = 0; n < 8; ++n) b[n] = Bs[kk][tx * 8 + n];
#pragma unroll
      for (int m = 0; m < 8; ++m)
#pragma unroll
        for (int n = 0; n < 8; ++n) acc[m][n] += a[m] * b[n];
    }
  }

#pragma unroll
  for (int m = 0; m < 8; ++m) {
    int grow = bm * 128 + ty * 8 + m;
#pragma unroll
    for (int n4 = 0; n4 < 2; ++n4) {
      int gcol = bn * 128 + tx * 8 + n4 * 4;
      float4 o;
      o.x = acc[m][n4 * 4 + 0] + bias[gcol + 0];
      o.y = acc[m][n4 * 4 + 1] + bias[gcol + 1];
      o.z = acc[m][n4 * 4 + 2] + bias[gcol + 2];
      o.w = acc[m][n4 * 4 + 3] + bias[gcol + 3];
      *reinterpret_cast<float4*>(C + (size_t)grow * DIM + gcol) = o;
    }
  }
}

extern "C" void kernel_launch(void* const* d_in, const int* in_sizes, int n_in,
                              void* d_out, int out_size, void* d_ws, size_t ws_size,
                              hipStream_t stream) {
  const float* x    = (const float*)d_in[0];
  const float* U    = (const float*)d_in[1];
  const float* V    = (const float*)d_in[2];
  const float* p    = (const float*)d_in[3];
  const float* bias = (const float*)d_in[4];
  float* out = (float*)d_out;

  float* M    = (float*)d_ws;          // 1024*1024 f32 = 4 MB
  float* tinu = M + (size_t)DIM * DIM; // 1024
  float* tinv = tinu + DIM;            // 1024
  float* sg   = tinv + DIM;            // 1024

  prep_k<<<512, 256, 0, stream>>>(U, V, tinu, tinv);
  sig_k<<<DIM / 256, 256, 0, stream>>>(p, sg);
  chain_k<<<DIM, 64, 0, stream>>>(U, V, tinu, tinv, sg, M);
  gemm_k<<<dim3(8, 32), 256, 0, stream>>>(x, M, bias, out);
}

// Round 3
// 424.738 us; speedup vs baseline: 3.5690x; 1.5314x over previous
//
#include <hip/hip_runtime.h>

#define DIM 1024
#define BATCH 4096

// ---------------------------------------------------------------------------
// Wave-wide sum via DPP (VALU pipe) -> wave-uniform result.
__device__ __forceinline__ float dpp_reduce_bcast(float x) {
  int v = __builtin_bit_cast(int, x);
#define DPP_STEP(ctrl)                                                        \
  {                                                                           \
    int s = __builtin_amdgcn_update_dpp(0, v, ctrl, 0xf, 0xf, true);          \
    v = __builtin_bit_cast(                                                   \
        int, __builtin_bit_cast(float, v) + __builtin_bit_cast(float, s));    \
  }
  DPP_STEP(0x111)  // row_shr:1
  DPP_STEP(0x112)  // row_shr:2
  DPP_STEP(0x114)  // row_shr:4
  DPP_STEP(0x118)  // row_shr:8
  DPP_STEP(0x142)  // row_bcast:15
  DPP_STEP(0x143)  // row_bcast:31
#undef DPP_STEP
  return __builtin_bit_cast(float, __builtin_amdgcn_readlane(v, 63));
}

// 4 interleaved reduce chains (independent -> pipeline through the VALU).
__device__ __forceinline__ void dpp_reduce4_bcast(float (&d)[4]) {
  int v0 = __builtin_bit_cast(int, d[0]);
  int v1 = __builtin_bit_cast(int, d[1]);
  int v2 = __builtin_bit_cast(int, d[2]);
  int v3 = __builtin_bit_cast(int, d[3]);
#define STEP4(ctrl)                                                           \
  {                                                                           \
    int s0 = __builtin_amdgcn_update_dpp(0, v0, ctrl, 0xf, 0xf, true);        \
    int s1 = __builtin_amdgcn_update_dpp(0, v1, ctrl, 0xf, 0xf, true);        \
    int s2 = __builtin_amdgcn_update_dpp(0, v2, ctrl, 0xf, 0xf, true);        \
    int s3 = __builtin_amdgcn_update_dpp(0, v3, ctrl, 0xf, 0xf, true);        \
    v0 = __builtin_bit_cast(int, __builtin_bit_cast(float, v0) +              \
                                     __builtin_bit_cast(float, s0));          \
    v1 = __builtin_bit_cast(int, __builtin_bit_cast(float, v1) +              \
                                     __builtin_bit_cast(float, s1));          \
    v2 = __builtin_bit_cast(int, __builtin_bit_cast(float, v2) +              \
                                     __builtin_bit_cast(float, s2));          \
    v3 = __builtin_bit_cast(int, __builtin_bit_cast(float, v3) +              \
                                     __builtin_bit_cast(float, s3));          \
  }
  STEP4(0x111) STEP4(0x112) STEP4(0x114) STEP4(0x118) STEP4(0x142) STEP4(0x143)
#undef STEP4
  d[0] = __builtin_bit_cast(float, __builtin_amdgcn_readlane(v0, 63));
  d[1] = __builtin_bit_cast(float, __builtin_amdgcn_readlane(v1, 63));
  d[2] = __builtin_bit_cast(float, __builtin_amdgcn_readlane(v2, 63));
  d[3] = __builtin_bit_cast(float, __builtin_amdgcn_readlane(v3, 63));
}

// Register layout: reg idx = q*4+j <-> element q*256 + lane*4 + j.
// Triangular structure: reflector (row) i of U/V has exact zeros before col i,
// so chunks q < (i>>8) contribute nothing -> compile-time CMIN per phase.

// 2/||row||^2 for all rows of U and V. One wave per row.
__global__ __launch_bounds__(256) void prep_k(const float* __restrict__ U,
                                              const float* __restrict__ V,
                                              float* __restrict__ tinu,
                                              float* __restrict__ tinv) {
  int gw = (blockIdx.x * 256 + threadIdx.x) >> 6;
  int lane = threadIdx.x & 63;
  if (gw >= 2048) return;
  const float* src = (gw < 1024) ? (U + (size_t)gw * DIM) : (V + (size_t)(gw - 1024) * DIM);
  float s = 0.f;
#pragma unroll
  for (int q = 0; q < 4; ++q) {
    float4 v = *reinterpret_cast<const float4*>(src + q * 256 + lane * 4);
    s += v.x * v.x + v.y * v.y + v.z * v.z + v.w * v.w;
  }
  float tot = dpp_reduce_bcast(s);
  if (lane == 0) {
    float val = 2.0f / tot;
    if (gw < 1024) tinu[gw] = val; else tinv[gw - 1024] = val;
  }
}

__global__ __launch_bounds__(256) void sig_k(const float* __restrict__ p, float* __restrict__ sg) {
  int i = blockIdx.x * 256 + threadIdx.x;
  if (i < DIM) {
    sg[i] = 0.1f + 0.9f / (1.0f + __expf(-p[i]));  // 0.9*sigmoid(p)+0.1
  }
}

// Pairwise dots c_ab = u_a . u_b (a<b) for each group of 4 consecutive
// reflectors IN APPLICATION ORDER (U ascending, V descending).
// Layout per group: (01,02,03,12,13,23).
__global__ __launch_bounds__(256) void pairs_k(const float* __restrict__ U,
                                               const float* __restrict__ V,
                                               float* __restrict__ cU,
                                               float* __restrict__ cV) {
  int gw = (blockIdx.x * 256 + threadIdx.x) >> 6;
  int lane = threadIdx.x & 63;
  if (gw >= 512) return;
  int isV = gw >= 256;
  int g = isV ? gw - 256 : gw;
  const float* R = isV ? V : U;
  int r0 = isV ? (DIM - 1 - 4 * g) : 4 * g;
  int dir = isV ? -1 : 1;
  float u[4][16];
#pragma unroll
  for (int rr = 0; rr < 4; ++rr) {
    const float* src = R + (size_t)(r0 + dir * rr) * DIM;
#pragma unroll
    for (int q = 0; q < 4; ++q) {
      float4 v = *reinterpret_cast<const float4*>(src + q * 256 + lane * 4);
      u[rr][q * 4 + 0] = v.x; u[rr][q * 4 + 1] = v.y;
      u[rr][q * 4 + 2] = v.z; u[rr][q * 4 + 3] = v.w;
    }
  }
  const int pa[6] = {0, 0, 0, 1, 1, 2};
  const int pb[6] = {1, 2, 3, 2, 3, 3};
  float* dst = (isV ? cV : cU) + (size_t)g * 6;
#pragma unroll
  for (int k = 0; k < 6; ++k) {
    float s = 0.f;
#pragma unroll
    for (int i = 0; i < 16; ++i) s = fmaf(u[pa[k]][i], u[pb[k]][i], s);
    s = dpp_reduce_bcast(s);
    if (lane == 0) dst[k] = s;
  }
}

template <int CMIN, int DIR>
__device__ __forceinline__ void load_group(float (&u)[4][16], const float* __restrict__ R,
                                           int o, int lane) {
  int r0 = (DIR > 0) ? o : (DIM - 1 - o);
#pragma unroll
  for (int rr = 0; rr < 4; ++rr) {
    const float* src = R + (size_t)(r0 + DIR * rr) * DIM;
#pragma unroll
    for (int q = 0; q < 4; ++q) {
      if (q >= CMIN) {
        float4 v = *reinterpret_cast<const float4*>(src + q * 256 + lane * 4);
        u[rr][q * 4 + 0] = v.x; u[rr][q * 4 + 1] = v.y;
        u[rr][q * 4 + 2] = v.z; u[rr][q * 4 + 3] = v.w;
      }
    }
  }
}

// Apply 4 reflectors via compact-WY: 4 dots on the UNMODIFIED row, forward
// substitution with precomputed c_ab, then one fused 4-way axpy. Exactly
// equal (in exact arithmetic) to applying the 4 reflections sequentially.
template <int CMIN>
__device__ __forceinline__ void apply_group(float (&t)[16], const float (&u)[4][16],
                                            float tau0, float tau1, float tau2, float tau3,
                                            const float* __restrict__ c) {
  float d[4];
#pragma unroll
  for (int rr = 0; rr < 4; ++rr) {
    float a0 = 0.f, a1 = 0.f, a2 = 0.f, a3 = 0.f;
#pragma unroll
    for (int q = 0; q < 4; ++q) {
      if (q >= CMIN) {
        a0 = fmaf(t[q * 4 + 0], u[rr][q * 4 + 0], a0);
        a1 = fmaf(t[q * 4 + 1], u[rr][q * 4 + 1], a1);
        a2 = fmaf(t[q * 4 + 2], u[rr][q * 4 + 2], a2);
        a3 = fmaf(t[q * 4 + 3], u[rr][q * 4 + 3], a3);
      }
    }
    d[rr] = (a0 + a1) + (a2 + a3);
  }
  dpp_reduce4_bcast(d);
  float al0 = tau0 * d[0];
  float al1 = tau1 * fmaf(-al0, c[0], d[1]);
  float al2 = tau2 * fmaf(-al1, c[3], fmaf(-al0, c[1], d[2]));
  float al3 = tau3 * fmaf(-al2, c[5], fmaf(-al1, c[4], fmaf(-al0, c[2], d[3])));
#pragma unroll
  for (int q = 0; q < 4; ++q) {
    if (q >= CMIN) {
#pragma unroll
      for (int j = 0; j < 4; ++j) {
        int i = q * 4 + j;
        t[i] = fmaf(-al3, u[3][i],
               fmaf(-al2, u[2][i],
               fmaf(-al1, u[1][i],
               fmaf(-al0, u[0][i], t[i]))));
      }
    }
  }
}

template <int CMIN, int DIR>
__device__ __forceinline__ void run_phase(float (&t)[16], const float* __restrict__ R,
                                          int o0, int o1,
                                          const float* __restrict__ taus,  // by row idx
                                          const float* __restrict__ cg,    // by group (o>>2)
                                          int lane) {
  float A[4][16], B[4][16];
  load_group<CMIN, DIR>(A, R, o0, lane);
  for (int o = o0; o < o1; o += 8) {
    load_group<CMIN, DIR>(B, R, o + 4, lane);
    {
      int r0 = (DIR > 0) ? o : (DIM - 1 - o);
      apply_group<CMIN>(t, A, taus[r0], taus[r0 + DIR], taus[r0 + 2 * DIR],
                        taus[r0 + 3 * DIR], cg + (size_t)(o >> 2) * 6);
    }
    if (o + 8 < o1) load_group<CMIN, DIR>(A, R, o + 8, lane);
    {
      int o2 = o + 4;
      int r0 = (DIR > 0) ? o2 : (DIM - 1 - o2);
      apply_group<CMIN>(t, B, taus[r0], taus[r0 + DIR], taus[r0 + 2 * DIR],
                        taus[r0 + 3 * DIR], cg + (size_t)(o2 >> 2) * 6);
    }
  }
}

// Build M = Q_U * diag(sig) * Q_V on identity rows. One wave per row.
__global__ __launch_bounds__(64, 1) void chain_k(const float* __restrict__ U,
                                                 const float* __restrict__ V,
                                                 const float* __restrict__ tinu,
                                                 const float* __restrict__ tinv,
                                                 const float* __restrict__ sg,
                                                 const float* __restrict__ cU,
                                                 const float* __restrict__ cV,
                                                 float* __restrict__ M) {
  const int row = blockIdx.x;
  const int lane = threadIdx.x;
  float t[16];
#pragma unroll
  for (int q = 0; q < 4; ++q)
#pragma unroll
    for (int j = 0; j < 4; ++j)
      t[q * 4 + j] = ((q * 256 + lane * 4 + j) == row) ? 1.0f : 0.0f;

  // U chain ascending; phase p covers i in [256p, 256p+256), cmin = p.
  run_phase<0, 1>(t, U, 0, 256, tinu, cU, lane);
  run_phase<1, 1>(t, U, 256, 512, tinu, cU, lane);
  run_phase<2, 1>(t, U, 512, 768, tinu, cU, lane);
  run_phase<3, 1>(t, U, 768, 1024, tinu, cU, lane);

  // sigma scaling (columns)
#pragma unroll
  for (int q = 0; q < 4; ++q) {
    float4 v = *reinterpret_cast<const float4*>(sg + q * 256 + lane * 4);
    t[q * 4 + 0] *= v.x; t[q * 4 + 1] *= v.y; t[q * 4 + 2] *= v.z; t[q * 4 + 3] *= v.w;
  }

  // V chain descending; order o covers rows 1023-o. cmin = (1023-o)>>8.
  run_phase<3, -1>(t, V, 0, 256, tinv, cV, lane);
  run_phase<2, -1>(t, V, 256, 512, tinv, cV, lane);
  run_phase<1, -1>(t, V, 512, 768, tinv, cV, lane);
  run_phase<0, -1>(t, V, 768, 1024, tinv, cV, lane);

#pragma unroll
  for (int q = 0; q < 4; ++q) {
    float4 v;
    v.x = t[q * 4 + 0]; v.y = t[q * 4 + 1]; v.z = t[q * 4 + 2]; v.w = t[q * 4 + 3];
    *reinterpret_cast<float4*>(M + (size_t)row * DIM + q * 256 + lane * 4) = v;
  }
}

// out[4096,1024] = x[4096,1024] @ M[1024,1024] + bias, f32 vector GEMM.
__global__ __launch_bounds__(256) void gemm_k(const float* __restrict__ A,
                                              const float* __restrict__ Bm,
                                              const float* __restrict__ bias,
                                              float* __restrict__ C) {
  __shared__ float As[16][132];
  __shared__ float Bs[16][132];
  const int tid = threadIdx.x;
  const int tx = tid & 15;
  const int ty = tid >> 4;
  const int bn = blockIdx.x;
  const int bm = blockIdx.y;
  const float* Ab = A + (size_t)bm * 128 * DIM;
  const float* Bb = Bm + (size_t)bn * 128;
  float acc[8][8] = {};

  for (int kb = 0; kb < DIM; kb += 16) {
    __syncthreads();
#pragma unroll
    for (int ii = 0; ii < 2; ++ii) {
      int f = tid + ii * 256;
      int r = f >> 2, k4 = (f & 3) << 2;
      float4 va = *reinterpret_cast<const float4*>(Ab + (size_t)r * DIM + kb + k4);
      As[k4 + 0][r] = va.x; As[k4 + 1][r] = va.y; As[k4 + 2][r] = va.z; As[k4 + 3][r] = va.w;
      int kB = f >> 5, n4 = (f & 31) << 2;
      float4 vb = *reinterpret_cast<const float4*>(Bb + (size_t)(kb + kB) * DIM + n4);
      *reinterpret_cast<float4*>(&Bs[kB][n4]) = vb;
    }
    __syncthreads();
#pragma unroll
    for (int kk = 0; kk < 16; ++kk) {
      float a[8], b[8];
#pragma unroll
      for (int m = 0; m < 8; ++m) a[m] = As[kk][ty * 8 + m];
#pragma unroll
      for (int n = 0; n < 8; ++n) b[n] = Bs[kk][tx * 8 + n];
#pragma unroll
      for (int m = 0; m < 8; ++m)
#pragma unroll
        for (int n = 0; n < 8; ++n) acc[m][n] += a[m] * b[n];
    }
  }

#pragma unroll
  for (int m = 0; m < 8; ++m) {
    int grow = bm * 128 + ty * 8 + m;
#pragma unroll
    for (int n4 = 0; n4 < 2; ++n4) {
      int gcol = bn * 128 + tx * 8 + n4 * 4;
      float4 o;
      o.x = acc[m][n4 * 4 + 0] + bias[gcol + 0];
      o.y = acc[m][n4 * 4 + 1] + bias[gcol + 1];
      o.z = acc[m][n4 * 4 + 2] + bias[gcol + 2];
      o.w = acc[m][n4 * 4 + 3] + bias[gcol + 3];
      *reinterpret_cast<float4*>(C + (size_t)grow * DIM + gcol) = o;
    }
  }
}

extern "C" void kernel_launch(void* const* d_in, const int* in_sizes, int n_in,
                              void* d_out, int out_size, void* d_ws, size_t ws_size,
                              hipStream_t stream) {
  const float* x    = (const float*)d_in[0];
  const float* U    = (const float*)d_in[1];
  const float* V    = (const float*)d_in[2];
  const float* p    = (const float*)d_in[3];
  const float* bias = (const float*)d_in[4];
  float* out = (float*)d_out;

  float* M    = (float*)d_ws;            // 1024*1024 f32 = 4 MB
  float* tinu = M + (size_t)DIM * DIM;   // 1024
  float* tinv = tinu + DIM;              // 1024
  float* sg   = tinv + DIM;              // 1024
  float* cU   = sg + DIM;                // 256*6
  float* cV   = cU + 256 * 6;            // 256*6

  prep_k<<<512, 256, 0, stream>>>(U, V, tinu, tinv);
  sig_k<<<DIM / 256, 256, 0, stream>>>(p, sg);
  pairs_k<<<128, 256, 0, stream>>>(U, V, cU, cV);
  chain_k<<<DIM, 64, 0, stream>>>(U, V, tinu, tinv, sg, cU, cV, M);
  gemm_k<<<dim3(8, 32), 256, 0, stream>>>(x, M, bias, out);
}

// Round 4
// 400.130 us; speedup vs baseline: 3.7885x; 1.0615x over previous
//
#include <hip/hip_runtime.h>

#define DIM 1024
#define BATCH 4096

// ---------------------------------------------------------------------------
// Wave-wide sum via DPP (VALU pipe) -> wave-uniform result.
__device__ __forceinline__ float dpp_reduce_bcast(float x) {
  int v = __builtin_bit_cast(int, x);
#define DPP_STEP(ctrl)                                                        \
  {                                                                           \
    int s = __builtin_amdgcn_update_dpp(0, v, ctrl, 0xf, 0xf, true);          \
    v = __builtin_bit_cast(                                                   \
        int, __builtin_bit_cast(float, v) + __builtin_bit_cast(float, s));    \
  }
  DPP_STEP(0x111)  // row_shr:1
  DPP_STEP(0x112)  // row_shr:2
  DPP_STEP(0x114)  // row_shr:4
  DPP_STEP(0x118)  // row_shr:8
  DPP_STEP(0x142)  // row_bcast:15
  DPP_STEP(0x143)  // row_bcast:31
#undef DPP_STEP
  return __builtin_bit_cast(float, __builtin_amdgcn_readlane(v, 63));
}

// 4 interleaved reduce chains (independent -> pipeline through the VALU).
__device__ __forceinline__ void dpp_reduce4_bcast(float (&d)[4]) {
  int v0 = __builtin_bit_cast(int, d[0]);
  int v1 = __builtin_bit_cast(int, d[1]);
  int v2 = __builtin_bit_cast(int, d[2]);
  int v3 = __builtin_bit_cast(int, d[3]);
#define STEP4(ctrl)                                                           \
  {                                                                           \
    int s0 = __builtin_amdgcn_update_dpp(0, v0, ctrl, 0xf, 0xf, true);        \
    int s1 = __builtin_amdgcn_update_dpp(0, v1, ctrl, 0xf, 0xf, true);        \
    int s2 = __builtin_amdgcn_update_dpp(0, v2, ctrl, 0xf, 0xf, true);        \
    int s3 = __builtin_amdgcn_update_dpp(0, v3, ctrl, 0xf, 0xf, true);        \
    v0 = __builtin_bit_cast(int, __builtin_bit_cast(float, v0) +              \
                                     __builtin_bit_cast(float, s0));          \
    v1 = __builtin_bit_cast(int, __builtin_bit_cast(float, v1) +              \
                                     __builtin_bit_cast(float, s1));          \
    v2 = __builtin_bit_cast(int, __builtin_bit_cast(float, v2) +              \
                                     __builtin_bit_cast(float, s2));          \
    v3 = __builtin_bit_cast(int, __builtin_bit_cast(float, v3) +              \
                                     __builtin_bit_cast(float, s3));          \
  }
  STEP4(0x111) STEP4(0x112) STEP4(0x114) STEP4(0x118) STEP4(0x142) STEP4(0x143)
#undef STEP4
  d[0] = __builtin_bit_cast(float, __builtin_amdgcn_readlane(v0, 63));
  d[1] = __builtin_bit_cast(float, __builtin_amdgcn_readlane(v1, 63));
  d[2] = __builtin_bit_cast(float, __builtin_amdgcn_readlane(v2, 63));
  d[3] = __builtin_bit_cast(float, __builtin_amdgcn_readlane(v3, 63));
}

// Register layout: reg idx = q*4+j <-> element q*256 + lane*4 + j.
// Reflector (row) i of U/V has exact zeros before col i -> compile-time CMIN.

// 2/||row||^2 for all rows of U and V. One wave per row.
__global__ __launch_bounds__(256) void prep_k(const float* __restrict__ U,
                                              const float* __restrict__ V,
                                              float* __restrict__ tinu,
                                              float* __restrict__ tinv) {
  int gw = (blockIdx.x * 256 + threadIdx.x) >> 6;
  int lane = threadIdx.x & 63;
  if (gw >= 2048) return;
  const float* src = (gw < 1024) ? (U + (size_t)gw * DIM) : (V + (size_t)(gw - 1024) * DIM);
  float s = 0.f;
#pragma unroll
  for (int q = 0; q < 4; ++q) {
    float4 v = *reinterpret_cast<const float4*>(src + q * 256 + lane * 4);
    s += v.x * v.x + v.y * v.y + v.z * v.z + v.w * v.w;
  }
  float tot = dpp_reduce_bcast(s);
  if (lane == 0) {
    float val = 2.0f / tot;
    if (gw < 1024) tinu[gw] = val; else tinv[gw - 1024] = val;
  }
}

__global__ __launch_bounds__(256) void sig_k(const float* __restrict__ p, float* __restrict__ sg) {
  int i = blockIdx.x * 256 + threadIdx.x;
  if (i < DIM) {
    sg[i] = 0.1f + 0.9f / (1.0f + __expf(-p[i]));  // 0.9*sigmoid(p)+0.1
  }
}

// Pairwise dots c_ab = u_a . u_b (a<b) per group of 4 consecutive reflectors
// IN APPLICATION ORDER (U ascending, V descending). Layout: (01,02,03,12,13,23).
__global__ __launch_bounds__(256) void pairs_k(const float* __restrict__ U,
                                               const float* __restrict__ V,
                                               float* __restrict__ cU,
                                               float* __restrict__ cV) {
  int gw = (blockIdx.x * 256 + threadIdx.x) >> 6;
  int lane = threadIdx.x & 63;
  if (gw >= 512) return;
  int isV = gw >= 256;
  int g = isV ? gw - 256 : gw;
  const float* R = isV ? V : U;
  int r0 = isV ? (DIM - 1 - 4 * g) : 4 * g;
  int dir = isV ? -1 : 1;
  float u[4][16];
#pragma unroll
  for (int rr = 0; rr < 4; ++rr) {
    const float* src = R + (size_t)(r0 + dir * rr) * DIM;
#pragma unroll
    for (int q = 0; q < 4; ++q) {
      float4 v = *reinterpret_cast<const float4*>(src + q * 256 + lane * 4);
      u[rr][q * 4 + 0] = v.x; u[rr][q * 4 + 1] = v.y;
      u[rr][q * 4 + 2] = v.z; u[rr][q * 4 + 3] = v.w;
    }
  }
  const int pa[6] = {0, 0, 0, 1, 1, 2};
  const int pb[6] = {1, 2, 3, 2, 3, 3};
  float* dst = (isV ? cV : cU) + (size_t)g * 6;
#pragma unroll
  for (int k = 0; k < 6; ++k) {
    float s = 0.f;
#pragma unroll
    for (int i = 0; i < 16; ++i) s = fmaf(u[pa[k]][i], u[pb[k]][i], s);
    s = dpp_reduce_bcast(s);
    if (lane == 0) dst[k] = s;
  }
}

template <int CMIN, int DIR>
__device__ __forceinline__ void load_group(float (&u)[4][16], const float* __restrict__ R,
                                           int o, int lane) {
  int r0 = (DIR > 0) ? o : (DIM - 1 - o);
#pragma unroll
  for (int rr = 0; rr < 4; ++rr) {
    const float* src = R + (size_t)(r0 + DIR * rr) * DIM;
#pragma unroll
    for (int q = 0; q < 4; ++q) {
      if (q >= CMIN) {
        float4 v = *reinterpret_cast<const float4*>(src + q * 256 + lane * 4);
        u[rr][q * 4 + 0] = v.x; u[rr][q * 4 + 1] = v.y;
        u[rr][q * 4 + 2] = v.z; u[rr][q * 4 + 3] = v.w;
      }
    }
  }
}

// Apply 4 reflectors via compact-WY: 4 dots on the UNMODIFIED row, forward
// substitution with precomputed c_ab, then one fused 4-way axpy.
template <int CMIN>
__device__ __forceinline__ void apply_group(float (&t)[16], const float (&u)[4][16],
                                            float tau0, float tau1, float tau2, float tau3,
                                            const float* __restrict__ c) {
  float d[4];
#pragma unroll
  for (int rr = 0; rr < 4; ++rr) {
    float a0 = 0.f, a1 = 0.f, a2 = 0.f, a3 = 0.f;
#pragma unroll
    for (int q = 0; q < 4; ++q) {
      if (q >= CMIN) {
        a0 = fmaf(t[q * 4 + 0], u[rr][q * 4 + 0], a0);
        a1 = fmaf(t[q * 4 + 1], u[rr][q * 4 + 1], a1);
        a2 = fmaf(t[q * 4 + 2], u[rr][q * 4 + 2], a2);
        a3 = fmaf(t[q * 4 + 3], u[rr][q * 4 + 3], a3);
      }
    }
    d[rr] = (a0 + a1) + (a2 + a3);
  }
  dpp_reduce4_bcast(d);
  float al0 = tau0 * d[0];
  float al1 = tau1 * fmaf(-al0, c[0], d[1]);
  float al2 = tau2 * fmaf(-al1, c[3], fmaf(-al0, c[1], d[2]));
  float al3 = tau3 * fmaf(-al2, c[5], fmaf(-al1, c[4], fmaf(-al0, c[2], d[3])));
#pragma unroll
  for (int q = 0; q < 4; ++q) {
    if (q >= CMIN) {
#pragma unroll
      for (int j = 0; j < 4; ++j) {
        int i = q * 4 + j;
        t[i] = fmaf(-al3, u[3][i],
               fmaf(-al2, u[2][i],
               fmaf(-al1, u[1][i],
               fmaf(-al0, u[0][i], t[i]))));
      }
    }
  }
}

template <int CMIN, int DIR>
__device__ __forceinline__ void run_phase(float (&t)[16], const float* __restrict__ R,
                                          int o0, int o1,
                                          const float* __restrict__ taus,  // by row idx
                                          const float* __restrict__ cg,    // by group (o>>2)
                                          int lane) {
  float A[4][16], B[4][16];
  load_group<CMIN, DIR>(A, R, o0, lane);
  for (int o = o0; o < o1; o += 8) {
    load_group<CMIN, DIR>(B, R, o + 4, lane);
    {
      int r0 = (DIR > 0) ? o : (DIM - 1 - o);
      apply_group<CMIN>(t, A, taus[r0], taus[r0 + DIR], taus[r0 + 2 * DIR],
                        taus[r0 + 3 * DIR], cg + (size_t)(o >> 2) * 6);
    }
    if (o + 8 < o1) load_group<CMIN, DIR>(A, R, o + 8, lane);
    {
      int o2 = o + 4;
      int r0 = (DIR > 0) ? o2 : (DIM - 1 - o2);
      apply_group<CMIN>(t, B, taus[r0], taus[r0 + DIR], taus[r0 + 2 * DIR],
                        taus[r0 + 3 * DIR], cg + (size_t)(o2 >> 2) * 6);
    }
  }
}

// Build QU' = (H0..H1023)*D rows (blocks 0..1023) and QV = (Hv1023..Hv0) rows
// (blocks 1024..2047) independently. 2048 waves -> 2 waves/SIMD: sibling wave
// fills the serial dot->reduce->fsub->axpy stalls.
__global__ __launch_bounds__(64) void chain_k(const float* __restrict__ U,
                                              const float* __restrict__ V,
                                              const float* __restrict__ tinu,
                                              const float* __restrict__ tinv,
                                              const float* __restrict__ sg,
                                              const float* __restrict__ cU,
                                              const float* __restrict__ cV,
                                              float* __restrict__ QUp,
                                              float* __restrict__ QV) {
  const int gw = blockIdx.x;
  const int row = gw & (DIM - 1);
  const int lane = threadIdx.x;
  float t[16];
#pragma unroll
  for (int q = 0; q < 4; ++q)
#pragma unroll
    for (int j = 0; j < 4; ++j)
      t[q * 4 + j] = ((q * 256 + lane * 4 + j) == row) ? 1.0f : 0.0f;

  float* dst;
  if (gw < DIM) {
    // U chain ascending; phase p covers i in [256p, 256p+256), cmin = p.
    run_phase<0, 1>(t, U, 0, 256, tinu, cU, lane);
    run_phase<1, 1>(t, U, 256, 512, tinu, cU, lane);
    run_phase<2, 1>(t, U, 512, 768, tinu, cU, lane);
    run_phase<3, 1>(t, U, 768, 1024, tinu, cU, lane);
    // fold D: scale columns by sg
#pragma unroll
    for (int q = 0; q < 4; ++q) {
      float4 v = *reinterpret_cast<const float4*>(sg + q * 256 + lane * 4);
      t[q * 4 + 0] *= v.x; t[q * 4 + 1] *= v.y; t[q * 4 + 2] *= v.z; t[q * 4 + 3] *= v.w;
    }
    dst = QUp + (size_t)row * DIM;
  } else {
    // V chain descending; order o covers row 1023-o. cmin = (1023-o)>>8.
    run_phase<3, -1>(t, V, 0, 256, tinv, cV, lane);
    run_phase<2, -1>(t, V, 256, 512, tinv, cV, lane);
    run_phase<1, -1>(t, V, 512, 768, tinv, cV, lane);
    run_phase<0, -1>(t, V, 768, 1024, tinv, cV, lane);
    dst = QV + (size_t)row * DIM;
  }

#pragma unroll
  for (int q = 0; q < 4; ++q) {
    float4 v;
    v.x = t[q * 4 + 0]; v.y = t[q * 4 + 1]; v.z = t[q * 4 + 2]; v.w = t[q * 4 + 3];
    *reinterpret_cast<float4*>(dst + q * 256 + lane * 4) = v;
  }
}

// M[1024,1024] = QU'[1024,1024] @ QV[1024,1024]. 64x64 tile, BK=16,
// 256 threads, 4x4 microtile -> 256 blocks (1/CU).
__global__ __launch_bounds__(256) void mgemm_k(const float* __restrict__ A,
                                               const float* __restrict__ Bm,
                                               float* __restrict__ C) {
  __shared__ float As[16][68];
  __shared__ float Bs[16][68];
  const int tid = threadIdx.x;
  const int tx = tid & 15;
  const int ty = tid >> 4;
  const int bn = blockIdx.x;  // 0..15
  const int bm = blockIdx.y;  // 0..15
  const float* Ab = A + (size_t)bm * 64 * DIM;
  const float* Bb = Bm + (size_t)bn * 64;
  float acc[4][4] = {};

  for (int kb = 0; kb < DIM; kb += 16) {
    __syncthreads();
    {
      // A tile: 64 rows x 16 k (256 float4)
      int r = tid >> 2, k4 = (tid & 3) << 2;
      float4 va = *reinterpret_cast<const float4*>(Ab + (size_t)r * DIM + kb + k4);
      As[k4 + 0][r] = va.x; As[k4 + 1][r] = va.y; As[k4 + 2][r] = va.z; As[k4 + 3][r] = va.w;
      // B tile: 16 k x 64 n (256 float4)
      int kB = tid >> 4, n4 = (tid & 15) << 2;
      float4 vb = *reinterpret_cast<const float4*>(Bb + (size_t)(kb + kB) * DIM + n4);
      *reinterpret_cast<float4*>(&Bs[kB][n4]) = vb;
    }
    __syncthreads();
#pragma unroll
    for (int kk = 0; kk < 16; ++kk) {
      float a[4], b[4];
#pragma unroll
      for (int m = 0; m < 4; ++m) a[m] = As[kk][ty * 4 + m];
#pragma unroll
      for (int n = 0; n < 4; ++n) b[n] = Bs[kk][tx * 4 + n];
#pragma unroll
      for (int m = 0; m < 4; ++m)
#pragma unroll
        for (int n = 0; n < 4; ++n) acc[m][n] += a[m] * b[n];
    }
  }

#pragma unroll
  for (int m = 0; m < 4; ++m) {
    int grow = bm * 64 + ty * 4 + m;
    int gcol = bn * 64 + tx * 4;
    float4 o;
    o.x = acc[m][0]; o.y = acc[m][1]; o.z = acc[m][2]; o.w = acc[m][3];
    *reinterpret_cast<float4*>(C + (size_t)grow * DIM + gcol) = o;
  }
}

// out[4096,1024] = x[4096,1024] @ M[1024,1024] + bias, f32 vector GEMM.
__global__ __launch_bounds__(256) void gemm_k(const float* __restrict__ A,
                                              const float* __restrict__ Bm,
                                              const float* __restrict__ bias,
                                              float* __restrict__ C) {
  __shared__ float As[16][132];
  __shared__ float Bs[16][132];
  const int tid = threadIdx.x;
  const int tx = tid & 15;
  const int ty = tid >> 4;
  const int bn = blockIdx.x;
  const int bm = blockIdx.y;
  const float* Ab = A + (size_t)bm * 128 * DIM;
  const float* Bb = Bm + (size_t)bn * 128;
  float acc[8][8] = {};

  for (int kb = 0; kb < DIM; kb += 16) {
    __syncthreads();
#pragma unroll
    for (int ii = 0; ii < 2; ++ii) {
      int f = tid + ii * 256;
      int r = f >> 2, k4 = (f & 3) << 2;
      float4 va = *reinterpret_cast<const float4*>(Ab + (size_t)r * DIM + kb + k4);
      As[k4 + 0][r] = va.x; As[k4 + 1][r] = va.y; As[k4 + 2][r] = va.z; As[k4 + 3][r] = va.w;
      int kB = f >> 5, n4 = (f & 31) << 2;
      float4 vb = *reinterpret_cast<const float4*>(Bb + (size_t)(kb + kB) * DIM + n4);
      *reinterpret_cast<float4*>(&Bs[kB][n4]) = vb;
    }
    __syncthreads();
#pragma unroll
    for (int kk = 0; kk < 16; ++kk) {
      float a[8], b[8];
#pragma unroll
      for (int m = 0; m < 8; ++m) a[m] = As[kk][ty * 8 + m];
#pragma unroll
      for (int n = 0; n < 8; ++n) b[n] = Bs[kk][tx * 8 + n];
#pragma unroll
      for (int m = 0; m < 8; ++m)
#pragma unroll
        for (int n = 0; n < 8; ++n) acc[m][n] += a[m] * b[n];
    }
  }

#pragma unroll
  for (int m = 0; m < 8; ++m) {
    int grow = bm * 128 + ty * 8 + m;
#pragma unroll
    for (int n4 = 0; n4 < 2; ++n4) {
      int gcol = bn * 128 + tx * 8 + n4 * 4;
      float4 o;
      o.x = acc[m][n4 * 4 + 0] + bias[gcol + 0];
      o.y = acc[m][n4 * 4 + 1] + bias[gcol + 1];
      o.z = acc[m][n4 * 4 + 2] + bias[gcol + 2];
      o.w = acc[m][n4 * 4 + 3] + bias[gcol + 3];
      *reinterpret_cast<float4*>(C + (size_t)grow * DIM + gcol) = o;
    }
  }
}

extern "C" void kernel_launch(void* const* d_in, const int* in_sizes, int n_in,
                              void* d_out, int out_size, void* d_ws, size_t ws_size,
                              hipStream_t stream) {
  const float* x    = (const float*)d_in[0];
  const float* U    = (const float*)d_in[1];
  const float* V    = (const float*)d_in[2];
  const float* p    = (const float*)d_in[3];
  const float* bias = (const float*)d_in[4];
  float* out = (float*)d_out;

  float* M    = (float*)d_ws;            // 1M floats = 4 MB
  float* QUp  = M + (size_t)DIM * DIM;   // 4 MB
  float* QV   = QUp + (size_t)DIM * DIM; // 4 MB
  float* tinu = QV + (size_t)DIM * DIM;  // 1024
  float* tinv = tinu + DIM;              // 1024
  float* sg   = tinv + DIM;              // 1024
  float* cU   = sg + DIM;                // 256*6
  float* cV   = cU + 256 * 6;            // 256*6

  prep_k<<<512, 256, 0, stream>>>(U, V, tinu, tinv);
  sig_k<<<DIM / 256, 256, 0, stream>>>(p, sg);
  pairs_k<<<128, 256, 0, stream>>>(U, V, cU, cV);
  chain_k<<<2 * DIM, 64, 0, stream>>>(U, V, tinu, tinv, sg, cU, cV, QUp, QV);
  mgemm_k<<<dim3(16, 16), 256, 0, stream>>>(QUp, QV, M);
  gemm_k<<<dim3(8, 32), 256, 0, stream>>>(x, M, bias, out);
}